// Round 8
// baseline (191.439 us; speedup 1.0000x reference)
//
#include <hip/hip_runtime.h>
#include <math.h>

#define NB 32
#define NA 5
#define NC 80
#define NH 38
#define NW 38
#define MAXT 50
#define CELLS (NH * NW)   /* 1444 */
#define CH (5 + NC)       /* 85 */
#define THREADS 256
#define NWAVES (THREADS / 64)
#define NCELLBLK 15       /* 15 blocks * 256 thr * 2 cells = 7680 >= 7220 */
#define NCLSBLK 13        /* 13 blocks * 4 waves = 52 >= 50 records */
#define NXBLK (NCELLBLK + NCLSBLK)   /* 28 */
#define NPAIRS 3610       /* 7220 / 2 */
#define NTOTBLK (NXBLK * NB)         /* 896 */

/* per-block partial sums (plain stores) + arrival counter (self-resetting) */
__device__ float g_part[NB][NXBLK];
__device__ int   g_cnt = 0;

__device__ __constant__ float c_anchors[10] = {
    1.3221f, 1.73145f, 3.19275f, 4.00944f, 5.05587f,
    8.09892f, 9.47112f, 4.84053f, 11.2364f, 10.0071f};

__device__ __forceinline__ float sigmoidf_(float v) {
    return 1.0f / (1.0f + expf(-v));
}

__device__ __forceinline__ float bbox_iou_(float ax, float ay, float aw, float ah,
                                           float bx, float by, float bw, float bh) {
    float mx = fminf(ax - aw * 0.5f, bx - bw * 0.5f);
    float Mx = fmaxf(ax + aw * 0.5f, bx + bw * 0.5f);
    float my = fminf(ay - ah * 0.5f, by - bh * 0.5f);
    float My = fmaxf(ay + ah * 0.5f, by + bh * 0.5f);
    float cw = aw + bw - (Mx - mx);
    float ch = ah + bh - (My - my);
    float inter = (cw > 0.0f && ch > 0.0f) ? cw * ch : 0.0f;
    float uni = aw * ah + bw * bh - inter;
    return inter / fmaxf(uni, 1e-12f);
}

/* hit test: iou>0.6 <=> inter > 0.375*(area_p+area_g), division-free.
   Cell path evaluates all 50 sequentially; class path evaluates the SAME
   per-record expression on lane u + ballot-OR -> bit-identical boolean. */
__device__ __forceinline__ bool hit50_(float px, float py, float pw, float ph,
                                       const float4* __restrict__ sb,
                                       const float* __restrict__ st) {
    float x1 = px - pw * 0.5f, x2 = px + pw * 0.5f;
    float y1 = py - ph * 0.5f, y2 = py + ph * 0.5f;
    float pthr = 0.375f * (pw * ph);
    bool hit = false;
    #pragma unroll
    for (int u = 0; u < MAXT; ++u) {
        float4 rb = sb[u];
        float ow = fminf(x2, rb.z) - fmaxf(x1, rb.x);
        float oh = fminf(y2, rb.w) - fmaxf(y1, rb.y);
        ow = fmaxf(ow, 0.0f);
        oh = fmaxf(oh, 0.0f);
        hit = hit | (ow * oh > pthr + st[u]);
    }
    return hit;
}

/* per-cell loss given raw channel values */
__device__ __forceinline__ float cell_loss_(float xr, float yr, float wr, float hr,
                                            float cr, int i, int j, int a,
                                            const float4* __restrict__ sb,
                                            const float* __restrict__ st) {
    float sx = sigmoidf_(xr), sy = sigmoidf_(yr), sc = sigmoidf_(cr);
    float px = sx + (float)i, py = sy + (float)j;
    float pw = expf(wr) * c_anchors[2 * a];
    float ph = expf(hr) * c_anchors[2 * a + 1];
    bool hit = hit50_(px, py, pw, ph, sb, st);
    float dx = sx - 0.5f, dy = sy - 0.5f;
    return 0.5f * (dx * dx + dy * dy + wr * wr + hr * hr)
         + (hit ? 0.0f : 0.5f * sc * sc);
}

// ---------------------------------------------------------------------------
// SINGLE dispatch. grid (NXBLK, NB) x 256, block-granularity role split
// (identical to R7), plus last-block finish:
//   - every block plain-stores its partial to g_part[b][bx]
//   - release: __threadfence() + device-scope counter increment
//   - the last-arriving block acquires (fence), strided-sums the 896
//     partials over its 256 threads, writes loss[0], resets the counter.
// No block ever waits -> deadlock-free; device-scope ops -> XCD-safe.
// ---------------------------------------------------------------------------
__global__ __launch_bounds__(THREADS) void region_main(const float* __restrict__ out,
                                                       const float* __restrict__ tgt,
                                                       float* __restrict__ loss) {
    const int bx = blockIdx.x;
    const int b = blockIdx.y;
    const int tid = threadIdx.x;
    const int wid = tid >> 6;
    const int lane = tid & 63;
    const bool isClass = (bx >= NCELLBLK);

    __shared__ float4 s_box[MAXT];
    __shared__ float  s_thr[MAXT];
    __shared__ int    s_win[MAXT];
    __shared__ int    s_off[MAXT];
    __shared__ int    s_cls[MAXT];
    __shared__ float  s_gx[MAXT], s_gy[MAXT], s_gw[MAXT], s_gh[MAXT];
    __shared__ int    s_bn[MAXT], s_gi[MAXT], s_gj[MAXT];
    __shared__ float  s_wpart[NWAVES];
    __shared__ int    s_flag;

    // ---- cell blocks: issue the 10 channel dwords FIRST (latency overlap) ----
    float2 x2, y2, w2, h2, q2;
    int a = 0, j = 0, i0 = 0, p0 = 0;
    if (!isClass) {
        p0 = bx * THREADS + tid;                              // pair index
        int p = p0 < NPAIRS ? p0 : NPAIRS - 1;                // clamp (uniform flow)
        int c0 = 2 * p;                                       // even; pair shares a,j
        a = c0 / CELLS;
        int r0 = c0 - a * CELLS;
        j = r0 / NW;
        i0 = r0 - j * NW;
        const long base = (((long)(b * NA + a)) * CH) * CELLS + r0;  // 8B-aligned
        x2 = *(const float2*)&out[base];
        y2 = *(const float2*)&out[base + CELLS];
        w2 = *(const float2*)&out[base + 2 * CELLS];
        h2 = *(const float2*)&out[base + 3 * CELLS];
        q2 = *(const float2*)&out[base + 4 * CELLS];
    }

    // ---- wave 0: build records (both roles); class blocks also resolve winners ----
    if (wid == 0) {
        const bool isrec = (lane < MAXT);
        float t0 = 0.f, t1 = 0.f, gx = 0.f, gy = 0.f, gw = 0.f, gh = 0.f;
        if (isrec) {
            const float* tp = tgt + (long)b * (MAXT * 5) + lane * 5;
            t0 = tp[0];
            t1 = tp[1];
            gx = t1 * NW;
            gy = tp[2] * NH;
            gw = tp[3] * NW;
            gh = tp[4] * NH;
        }
        // valid = cumprod(t1 != 0): no zero slot at or before me
        unsigned long long nz = __ballot(isrec && (t1 != 0.0f));
        bool valid = isrec && (((~nz) & ((2ULL << lane) - 1ULL)) == 0ULL);

        float4 box;
        float thr;
        if (valid) {
            box.x = gx - gw * 0.5f; box.y = gy - gh * 0.5f;
            box.z = gx + gw * 0.5f; box.w = gy + gh * 0.5f;
            thr = 0.375f * (gw * gh);
        } else {
            box.x = box.y = box.z = box.w = 0.0f;   // degenerate: never hits
            thr = 3e38f;
        }
        if (isrec) {
            s_box[lane] = box;
            s_thr[lane] = thr;
        }

        if (isClass) {
            // best anchor (first max wins, matching argmax)
            int bn = 0;
            float best = -1.0f;
            for (int aa = 0; aa < NA; ++aa) {
                float aw = c_anchors[2 * aa], ah = c_anchors[2 * aa + 1];
                float inter = fminf(gw, aw) * fminf(gh, ah);
                float uni = gw * gh + aw * ah - inter;
                float iou = inter / fmaxf(uni, 1e-12f);
                if (iou > best) { best = iou; bn = aa; }
            }
            int gi = (int)floorf(gx); gi = gi < 0 ? 0 : (gi > NW - 1 ? NW - 1 : gi);
            int gj = (int)floorf(gy); gj = gj < 0 ? 0 : (gj > NH - 1 ? NH - 1 : gj);
            int key = valid ? (bn * CELLS + gj * NW + gi) : -1;

            // winner = valid and no LATER slot with the same key (register-only)
            unsigned long long eq = 0ULL;
            for (int u = 0; u < MAXT; ++u) {
                int ku = __shfl(key, u);
                eq |= (unsigned long long)(ku == key) << u;
            }
            bool winner = valid && ((eq & ~((2ULL << lane) - 1ULL)) == 0ULL);

            if (isrec) {
                s_win[lane] = winner ? 1 : 0;
                int cls = (int)t0; cls = cls < 0 ? 0 : (cls > NC - 1 ? NC - 1 : cls);
                s_cls[lane] = cls;
                s_off[lane] = (bn * CH + 5) * CELLS + gj * NW + gi;
                s_gx[lane] = gx; s_gy[lane] = gy; s_gw[lane] = gw; s_gh[lane] = gh;
                s_bn[lane] = bn; s_gi[lane] = gi; s_gj[lane] = gj;
            }
        }
    }
    __syncthreads();

    if (!isClass) {
        // ---------------- cell blocks ----------------
        float cs = cell_loss_(x2.x, y2.x, w2.x, h2.x, q2.x, i0,     j, a, s_box, s_thr)
                 + cell_loss_(x2.y, y2.y, w2.y, h2.y, q2.y, i0 + 1, j, a, s_box, s_thr);
        if (p0 >= NPAIRS) cs = 0.0f;

        for (int off = 32; off > 0; off >>= 1) cs += __shfl_down(cs, off);
        if (lane == 0) s_wpart[wid] = cs;
    } else {
        // ---------------- class blocks: one wave per record ----------------
        const int rec = __builtin_amdgcn_readfirstlane((bx - NCELLBLK) * NWAVES + wid); // 0..51
        float closs = 0.0f;
        if (rec < MAXT && s_win[rec]) {
            const int off_c = s_off[rec];
            const int cls = s_cls[rec];
            const float* cp = out + (long)b * (NA * CH * CELLS) + off_c;
            // class log-softmax (81 strided lines, one per lane)
            float v0 = cp[(long)lane * CELLS];                              // classes 0..63
            float v1 = (lane < NC - 64) ? cp[(long)(64 + lane) * CELLS] : -INFINITY;
            float vc = cp[(long)cls * CELLS];                               // picked class
            float m = fmaxf(v0, v1);
            for (int off = 32; off > 0; off >>= 1)
                m = fmaxf(m, __shfl_down(m, off));
            m = __shfl(m, 0);
            float e = expf(v0 - m) + ((lane < NC - 64) ? expf(v1 - m) : 0.0f);
            for (int off = 32; off > 0; off >>= 1)
                e += __shfl_down(e, off);

            // matched-cell correction (wave-uniform broadcast loads)
            float gx = s_gx[rec], gy = s_gy[rec], gw = s_gw[rec], gh = s_gh[rec];
            int bn = s_bn[rec], gi = s_gi[rec], gj = s_gj[rec];
            float aw = c_anchors[2 * bn], ah = c_anchors[2 * bn + 1];
            long rb = (((long)(b * NA + bn)) * CH) * CELLS + gj * NW + gi;
            float xr = out[rb];
            float yr = out[rb + CELLS];
            float wr = out[rb + 2 * CELLS];
            float hr = out[rb + 3 * CELLS];
            float cr = out[rb + 4 * CELLS];
            float sx = sigmoidf_(xr), sy = sigmoidf_(yr), sc = sigmoidf_(cr);
            float px = sx + (float)gi, py = sy + (float)gj;
            float pw = expf(wr) * aw, ph = expf(hr) * ah;
            float iou_gt = bbox_iou_(gx, gy, gw, gh, px, py, pw, ph);

            // hit test distributed: lane u evaluates record u (same expression
            // as hit50_'s term u -> bit-identical), OR via ballot
            float x1 = px - pw * 0.5f, xx2 = px + pw * 0.5f;
            float y1 = py - ph * 0.5f, yy2 = py + ph * 0.5f;
            float pthr = 0.375f * (pw * ph);
            bool myhit = false;
            if (lane < MAXT) {
                float4 rbx = s_box[lane];
                float ow = fminf(xx2, rbx.z) - fmaxf(x1, rbx.x);
                float oh = fminf(yy2, rbx.w) - fmaxf(y1, rbx.y);
                ow = fmaxf(ow, 0.0f);
                oh = fmaxf(oh, 0.0f);
                myhit = (ow * oh > pthr + s_thr[lane]);
            }
            bool rhit = (__ballot(myhit) != 0ULL);
            float h01 = rhit ? 0.0f : 1.0f;

            if (lane == 0) {
                float txv = gx - (float)gi, tyv = gy - (float)gj;
                float twv = logf(fmaxf(gw, 1e-12f) / aw);
                float thv = logf(fmaxf(gh, 1e-12f) / ah);
                float dsc = sc - iou_gt;
                float corr = 0.5f * ((sx - txv) * (sx - txv) - (sx - 0.5f) * (sx - 0.5f)
                                   + (sy - tyv) * (sy - tyv) - (sy - 0.5f) * (sy - 0.5f)
                                   + (wr - twv) * (wr - twv) - wr * wr
                                   + (hr - thv) * (hr - thv) - hr * hr)
                           + 0.5f * (5.0f * dsc * dsc - h01 * sc * sc);
                closs = (m + logf(e) - vc) + corr;
            }
        }
        if (lane == 0) s_wpart[wid] = closs;
    }

    // ---- block partial -> g_part (plain store), release, arrival count ----
    __syncthreads();
    if (tid == 0) {
        float s = 0.0f;
        for (int w = 0; w < NWAVES; ++w) s += s_wpart[w];
        g_part[b][bx] = s;
        __threadfence();                       // release: partial visible device-wide
        int old = atomicAdd(&g_cnt, 1);        // device-scope by default
        s_flag = (old == NTOTBLK - 1) ? 1 : 0;
    }
    __syncthreads();

    // ---- last-arriving block: acquire, sum 896 partials, write loss ----
    if (s_flag) {                              // block-uniform
        __threadfence();                       // acquire: see all partials
        float v = 0.0f;
        for (int idx = tid; idx < NTOTBLK; idx += THREADS)
            v += ((const float*)g_part)[idx];
        for (int off = 32; off > 0; off >>= 1) v += __shfl_down(v, off);
        if (lane == 0) s_wpart[wid] = v;       // reuse: safe, barrier above
        __syncthreads();                       // block-uniform path
        if (tid == 0) {
            float s = 0.0f;
            for (int w = 0; w < NWAVES; ++w) s += s_wpart[w];
            loss[0] = s;
            atomicExch(&g_cnt, 0);             // reset for next graph replay
        }
    }
}

extern "C" void kernel_launch(void* const* d_in, const int* in_sizes, int n_in,
                              void* d_out, int out_size, void* d_ws, size_t ws_size,
                              hipStream_t stream) {
    const float* output = (const float*)d_in[0];
    const float* target = (const float*)d_in[1];
    // d_in[2] = features: unused by the reference. d_ws: unused.
    float* loss = (float*)d_out;

    dim3 grid(NXBLK, NB);
    region_main<<<grid, THREADS, 0, stream>>>(output, target, loss);
}

// Round 9
// 166.568 us; speedup vs baseline: 1.1493x; 1.1493x over previous
//
#include <hip/hip_runtime.h>
#include <math.h>

#define NB 32
#define NA 5
#define NC 80
#define NH 38
#define NW 38
#define MAXT 50
#define CELLS (NH * NW)   /* 1444 */
#define CH (5 + NC)       /* 85 */
#define THREADS 256
#define NWAVES (THREADS / 64)
#define NCELLBLK 15       /* 15 blocks * 256 thr * 2 cells = 7680 >= 7220 */
#define NCLSBLK 13        /* 13 blocks * 4 waves = 52 >= 50 records */
#define NXBLK (NCELLBLK + NCLSBLK)   /* 28 */
#define NPAIRS 3610       /* 7220 / 2 */

/* main -> finish handoff: per-block partial sums (plain stores, no atomics) */
__device__ float g_part[NB][NXBLK];

__device__ __constant__ float c_anchors[10] = {
    1.3221f, 1.73145f, 3.19275f, 4.00944f, 5.05587f,
    8.09892f, 9.47112f, 4.84053f, 11.2364f, 10.0071f};

__device__ __forceinline__ float sigmoidf_(float v) {
    return 1.0f / (1.0f + expf(-v));
}

__device__ __forceinline__ float bbox_iou_(float ax, float ay, float aw, float ah,
                                           float bx, float by, float bw, float bh) {
    float mx = fminf(ax - aw * 0.5f, bx - bw * 0.5f);
    float Mx = fmaxf(ax + aw * 0.5f, bx + bw * 0.5f);
    float my = fminf(ay - ah * 0.5f, by - bh * 0.5f);
    float My = fmaxf(ay + ah * 0.5f, by + bh * 0.5f);
    float cw = aw + bw - (Mx - mx);
    float ch = ah + bh - (My - my);
    float inter = (cw > 0.0f && ch > 0.0f) ? cw * ch : 0.0f;
    float uni = aw * ah + bw * bh - inter;
    return inter / fmaxf(uni, 1e-12f);
}

/* hit test: iou>0.6 <=> inter > 0.375*(area_p+area_g), division-free.
   Cell path evaluates all 50 sequentially; class path evaluates the SAME
   per-record expression on lane u + ballot-OR -> bit-identical boolean. */
__device__ __forceinline__ bool hit50_(float px, float py, float pw, float ph,
                                       const float4* __restrict__ sb,
                                       const float* __restrict__ st) {
    float x1 = px - pw * 0.5f, x2 = px + pw * 0.5f;
    float y1 = py - ph * 0.5f, y2 = py + ph * 0.5f;
    float pthr = 0.375f * (pw * ph);
    bool hit = false;
    #pragma unroll
    for (int u = 0; u < MAXT; ++u) {
        float4 rb = sb[u];
        float ow = fminf(x2, rb.z) - fmaxf(x1, rb.x);
        float oh = fminf(y2, rb.w) - fmaxf(y1, rb.y);
        ow = fmaxf(ow, 0.0f);
        oh = fmaxf(oh, 0.0f);
        hit = hit | (ow * oh > pthr + st[u]);
    }
    return hit;
}

/* per-cell loss given raw channel values */
__device__ __forceinline__ float cell_loss_(float xr, float yr, float wr, float hr,
                                            float cr, int i, int j, int a,
                                            const float4* __restrict__ sb,
                                            const float* __restrict__ st) {
    float sx = sigmoidf_(xr), sy = sigmoidf_(yr), sc = sigmoidf_(cr);
    float px = sx + (float)i, py = sy + (float)j;
    float pw = expf(wr) * c_anchors[2 * a];
    float ph = expf(hr) * c_anchors[2 * a + 1];
    bool hit = hit50_(px, py, pw, ph, sb, st);
    float dx = sx - 0.5f, dy = sy - 0.5f;
    return 0.5f * (dx * dx + dy * dy + wr * wr + hr * hr)
         + (hit ? 0.0f : 0.5f * sc * sc);
}

// ---------------------------------------------------------------------------
// Single main kernel, grid (NXBLK, NB) x 256, block-granularity role split.
// Every block's wave 0 rebuilds the 50 GT boxes/thresholds from the 1KB
// target record (ballot valid, ~30 VALU — hides under the block's own
// global loads; no prep kernel, no serialization).
//   bx <  15 (cell blocks): 2 cells/thread float2 loads; 50-record overlap
//       loop; no winner resolution, no class work, no atomics.
//   bx >= 15 (class blocks): wave 0 additionally resolves winners (register
//       shfl loop) + record metadata -> LDS; then each wave owns one record:
//       class log-softmax + the matched-cell correction
//       corr = [matched loss] - [uniform unmatched formula]
//       (hit test distributed lane-per-record + ballot, bit-identical).
// Each block stores its partial to g_part[b][bx]; finish kernel sums 896.
// ---------------------------------------------------------------------------
__global__ __launch_bounds__(THREADS) void region_main(const float* __restrict__ out,
                                                       const float* __restrict__ tgt) {
    const int bx = blockIdx.x;
    const int b = blockIdx.y;
    const int tid = threadIdx.x;
    const int wid = tid >> 6;
    const int lane = tid & 63;
    const bool isClass = (bx >= NCELLBLK);

    __shared__ float4 s_box[MAXT];
    __shared__ float  s_thr[MAXT];
    __shared__ int    s_win[MAXT];
    __shared__ int    s_off[MAXT];
    __shared__ int    s_cls[MAXT];
    __shared__ float  s_gx[MAXT], s_gy[MAXT], s_gw[MAXT], s_gh[MAXT];
    __shared__ int    s_bn[MAXT], s_gi[MAXT], s_gj[MAXT];
    __shared__ float  s_wpart[NWAVES];

    // ---- cell blocks: issue the 10 channel dwords FIRST (latency overlap) ----
    float2 x2, y2, w2, h2, q2;
    int a = 0, j = 0, i0 = 0, p0 = 0;
    if (!isClass) {
        p0 = bx * THREADS + tid;                              // pair index
        int p = p0 < NPAIRS ? p0 : NPAIRS - 1;                // clamp (uniform flow)
        int c0 = 2 * p;                                       // even; pair shares a,j
        a = c0 / CELLS;
        int r0 = c0 - a * CELLS;
        j = r0 / NW;
        i0 = r0 - j * NW;
        const long base = (((long)(b * NA + a)) * CH) * CELLS + r0;  // 8B-aligned
        x2 = *(const float2*)&out[base];
        y2 = *(const float2*)&out[base + CELLS];
        w2 = *(const float2*)&out[base + 2 * CELLS];
        h2 = *(const float2*)&out[base + 3 * CELLS];
        q2 = *(const float2*)&out[base + 4 * CELLS];
    }

    // ---- wave 0: build records (both roles); class blocks also resolve winners ----
    if (wid == 0) {
        const bool isrec = (lane < MAXT);
        float t0 = 0.f, t1 = 0.f, gx = 0.f, gy = 0.f, gw = 0.f, gh = 0.f;
        if (isrec) {
            const float* tp = tgt + (long)b * (MAXT * 5) + lane * 5;
            t0 = tp[0];
            t1 = tp[1];
            gx = t1 * NW;
            gy = tp[2] * NH;
            gw = tp[3] * NW;
            gh = tp[4] * NH;
        }
        // valid = cumprod(t1 != 0): no zero slot at or before me
        unsigned long long nz = __ballot(isrec && (t1 != 0.0f));
        bool valid = isrec && (((~nz) & ((2ULL << lane) - 1ULL)) == 0ULL);

        float4 box;
        float thr;
        if (valid) {
            box.x = gx - gw * 0.5f; box.y = gy - gh * 0.5f;
            box.z = gx + gw * 0.5f; box.w = gy + gh * 0.5f;
            thr = 0.375f * (gw * gh);
        } else {
            box.x = box.y = box.z = box.w = 0.0f;   // degenerate: never hits
            thr = 3e38f;
        }
        if (isrec) {
            s_box[lane] = box;
            s_thr[lane] = thr;
        }

        if (isClass) {
            // best anchor (first max wins, matching argmax)
            int bn = 0;
            float best = -1.0f;
            for (int aa = 0; aa < NA; ++aa) {
                float aw = c_anchors[2 * aa], ah = c_anchors[2 * aa + 1];
                float inter = fminf(gw, aw) * fminf(gh, ah);
                float uni = gw * gh + aw * ah - inter;
                float iou = inter / fmaxf(uni, 1e-12f);
                if (iou > best) { best = iou; bn = aa; }
            }
            int gi = (int)floorf(gx); gi = gi < 0 ? 0 : (gi > NW - 1 ? NW - 1 : gi);
            int gj = (int)floorf(gy); gj = gj < 0 ? 0 : (gj > NH - 1 ? NH - 1 : gj);
            int key = valid ? (bn * CELLS + gj * NW + gi) : -1;

            // winner = valid and no LATER slot with the same key (register-only)
            unsigned long long eq = 0ULL;
            for (int u = 0; u < MAXT; ++u) {
                int ku = __shfl(key, u);
                eq |= (unsigned long long)(ku == key) << u;
            }
            bool winner = valid && ((eq & ~((2ULL << lane) - 1ULL)) == 0ULL);

            if (isrec) {
                s_win[lane] = winner ? 1 : 0;
                int cls = (int)t0; cls = cls < 0 ? 0 : (cls > NC - 1 ? NC - 1 : cls);
                s_cls[lane] = cls;
                s_off[lane] = (bn * CH + 5) * CELLS + gj * NW + gi;
                s_gx[lane] = gx; s_gy[lane] = gy; s_gw[lane] = gw; s_gh[lane] = gh;
                s_bn[lane] = bn; s_gi[lane] = gi; s_gj[lane] = gj;
            }
        }
    }
    __syncthreads();

    if (!isClass) {
        // ---------------- cell blocks ----------------
        float cs = cell_loss_(x2.x, y2.x, w2.x, h2.x, q2.x, i0,     j, a, s_box, s_thr)
                 + cell_loss_(x2.y, y2.y, w2.y, h2.y, q2.y, i0 + 1, j, a, s_box, s_thr);
        if (p0 >= NPAIRS) cs = 0.0f;

        for (int off = 32; off > 0; off >>= 1) cs += __shfl_down(cs, off);
        if (lane == 0) s_wpart[wid] = cs;
    } else {
        // ---------------- class blocks: one wave per record ----------------
        const int rec = __builtin_amdgcn_readfirstlane((bx - NCELLBLK) * NWAVES + wid); // 0..51
        float closs = 0.0f;
        if (rec < MAXT && s_win[rec]) {
            const int off_c = s_off[rec];
            const int cls = s_cls[rec];
            const float* cp = out + (long)b * (NA * CH * CELLS) + off_c;
            // class log-softmax (81 strided lines, one per lane)
            float v0 = cp[(long)lane * CELLS];                              // classes 0..63
            float v1 = (lane < NC - 64) ? cp[(long)(64 + lane) * CELLS] : -INFINITY;
            float vc = cp[(long)cls * CELLS];                               // picked class
            float m = fmaxf(v0, v1);
            for (int off = 32; off > 0; off >>= 1)
                m = fmaxf(m, __shfl_down(m, off));
            m = __shfl(m, 0);
            float e = expf(v0 - m) + ((lane < NC - 64) ? expf(v1 - m) : 0.0f);
            for (int off = 32; off > 0; off >>= 1)
                e += __shfl_down(e, off);

            // matched-cell correction (wave-uniform broadcast loads)
            float gx = s_gx[rec], gy = s_gy[rec], gw = s_gw[rec], gh = s_gh[rec];
            int bn = s_bn[rec], gi = s_gi[rec], gj = s_gj[rec];
            float aw = c_anchors[2 * bn], ah = c_anchors[2 * bn + 1];
            long rb = (((long)(b * NA + bn)) * CH) * CELLS + gj * NW + gi;
            float xr = out[rb];
            float yr = out[rb + CELLS];
            float wr = out[rb + 2 * CELLS];
            float hr = out[rb + 3 * CELLS];
            float cr = out[rb + 4 * CELLS];
            float sx = sigmoidf_(xr), sy = sigmoidf_(yr), sc = sigmoidf_(cr);
            float px = sx + (float)gi, py = sy + (float)gj;
            float pw = expf(wr) * aw, ph = expf(hr) * ah;
            float iou_gt = bbox_iou_(gx, gy, gw, gh, px, py, pw, ph);

            // hit test distributed: lane u evaluates record u (same expression
            // as hit50_'s term u -> bit-identical), OR via ballot
            float x1 = px - pw * 0.5f, xx2 = px + pw * 0.5f;
            float y1 = py - ph * 0.5f, yy2 = py + ph * 0.5f;
            float pthr = 0.375f * (pw * ph);
            bool myhit = false;
            if (lane < MAXT) {
                float4 rbx = s_box[lane];
                float ow = fminf(xx2, rbx.z) - fmaxf(x1, rbx.x);
                float oh = fminf(yy2, rbx.w) - fmaxf(y1, rbx.y);
                ow = fmaxf(ow, 0.0f);
                oh = fmaxf(oh, 0.0f);
                myhit = (ow * oh > pthr + s_thr[lane]);
            }
            bool rhit = (__ballot(myhit) != 0ULL);
            float h01 = rhit ? 0.0f : 1.0f;

            if (lane == 0) {
                float txv = gx - (float)gi, tyv = gy - (float)gj;
                float twv = logf(fmaxf(gw, 1e-12f) / aw);
                float thv = logf(fmaxf(gh, 1e-12f) / ah);
                float dsc = sc - iou_gt;
                float corr = 0.5f * ((sx - txv) * (sx - txv) - (sx - 0.5f) * (sx - 0.5f)
                                   + (sy - tyv) * (sy - tyv) - (sy - 0.5f) * (sy - 0.5f)
                                   + (wr - twv) * (wr - twv) - wr * wr
                                   + (hr - thv) * (hr - thv) - hr * hr)
                           + 0.5f * (5.0f * dsc * dsc - h01 * sc * sc);
                closs = (m + logf(e) - vc) + corr;
            }
        }
        if (lane == 0) s_wpart[wid] = closs;
    }

    __syncthreads();
    if (tid == 0) {
        float s = 0.0f;
        for (int w = 0; w < NWAVES; ++w) s += s_wpart[w];
        g_part[b][bx] = s;
    }
}

// ---------------------------------------------------------------------------
// Finish: one block sums the 896 block partials -> loss[0]. No atomics.
// ---------------------------------------------------------------------------
__global__ __launch_bounds__(1024) void region_finish(float* __restrict__ loss) {
    const int tid = threadIdx.x;
    const int wid = tid >> 6;
    const int lane = tid & 63;
    __shared__ float sp[16];

    float v = 0.0f;
    if (tid < NB * NXBLK) v = ((const float*)g_part)[tid];

    for (int off = 32; off > 0; off >>= 1) v += __shfl_down(v, off);
    if (lane == 0) sp[wid] = v;
    __syncthreads();
    if (tid == 0) {
        float s = 0.0f;
        for (int w = 0; w < 16; ++w) s += sp[w];
        loss[0] = s;
    }
}

extern "C" void kernel_launch(void* const* d_in, const int* in_sizes, int n_in,
                              void* d_out, int out_size, void* d_ws, size_t ws_size,
                              hipStream_t stream) {
    const float* output = (const float*)d_in[0];
    const float* target = (const float*)d_in[1];
    // d_in[2] = features: unused by the reference. d_ws: unused.
    float* loss = (float*)d_out;

    dim3 grid(NXBLK, NB);
    region_main<<<grid, THREADS, 0, stream>>>(output, target);
    region_finish<<<1, 1024, 0, stream>>>(loss);
}